// Round 1
// baseline (461.222 us; speedup 1.0000x reference)
//
#include <hip/hip_runtime.h>

typedef short short8 __attribute__((ext_vector_type(8)));
typedef float f32x4 __attribute__((ext_vector_type(4)));

#define NPTS 4096
#define BATCH 8
#define PTOT (BATCH*NPTS)      // 32768
#define FEATS 128
#define KK 20
#define OUTC 64

__device__ __forceinline__ unsigned short f2bf(float f){
  union { float f; unsigned u; } v; v.f = f;
  unsigned r = v.u + 0x7FFFu + ((v.u >> 16) & 1u);
  return (unsigned short)(r >> 16);
}

// feature [B,128,N] f32  ->  flat [B*N, 128] bf16
__global__ void k_transpose(const float* __restrict__ f, unsigned short* __restrict__ flat){
  __shared__ float tile[32][33];
  int b = blockIdx.z, c0 = blockIdx.y*32, n0 = blockIdx.x*32;
  int tx = threadIdx.x, ty = threadIdx.y;   // (32,8)
  const float* src = f + ((size_t)b*FEATS + c0)*NPTS + n0;
  #pragma unroll
  for(int i=0;i<4;i++) tile[ty+8*i][tx] = src[(size_t)(ty+8*i)*NPTS + tx];
  __syncthreads();
  unsigned short* dst = flat + ((size_t)b*NPTS + n0)*FEATS + c0;
  #pragma unroll
  for(int i=0;i<4;i++) dst[(size_t)(ty+8*i)*FEATS + tx] = f2bf(tile[tx][ty+8*i]);
}

__global__ __launch_bounds__(256) void k_main(
    const unsigned short* __restrict__ flat,
    const float* __restrict__ perm_g,
    const float* __restrict__ convw,
    const float* __restrict__ convb,
    const int*   __restrict__ idx_g,
    float* __restrict__ out,
    float* __restrict__ stats)
{
  const int t    = threadIdx.x;
  const int lane = t & 63;
  const int w    = t >> 6;      // wave 0..3
  const int l15  = lane & 15;
  const int lg   = lane >> 4;   // 0..3

  __shared__ __align__(16) unsigned short perm_s[32*32];   // [k][s] bf16, zero-padded
  __shared__ __align__(16) unsigned short spir[32*128];    // [k][c] bf16, rows 20..31 zero
  __shared__ __align__(16) unsigned short tmp[32*128];     // view layout [k'][c'] bf16, XOR-swizzled
  __shared__ int sidx[KK];

  // --- hoist conv_w A-fragments (constant across all points) ---
  // A[o][c'] : o = w*16 + l15 ; c' = ks*32 + lg*8 + j
  short8 wf[4];
  {
    const float* wr = convw + (size_t)(w*16 + l15)*FEATS;
    #pragma unroll
    for(int ks=0;ks<4;ks++){
      short8 v;
      #pragma unroll
      for(int j=0;j<8;j++) v[j] = (short)f2bf(wr[ks*32 + lg*8 + j]);
      wf[ks] = v;
    }
  }
  float bias[4];
  #pragma unroll
  for(int r=0;r<4;r++) bias[r] = convb[w*16 + lg*4 + r];

  float bsum[4] = {0.f,0.f,0.f,0.f}, bsq[4] = {0.f,0.f,0.f,0.f};

  for(int pi=0; pi<8; pi++){
    const int p = blockIdx.x*8 + pi;

    // ---- phase A: indices + perm stage + zero spir pad rows ----
    if(t < KK) sidx[t] = idx_g[(size_t)p*KK + t];
    for(int e=t; e<1024; e+=256){
      int k = e>>5, s = e&31;
      perm_s[e] = (k<KK && s<KK) ? f2bf(perm_g[(size_t)p*400 + k*20 + s])
                                 : (unsigned short)0;
    }
    {
      unsigned int* z = (unsigned int*)(spir + 20*128);
      for(int e=t; e<768; e+=256) z[e] = 0u;
    }
    __syncthreads();

    // ---- phase B: gather 20 neighbor rows (256B each, coalesced) ----
    #pragma unroll
    for(int it=0; it<5; it++){
      int k = it*4 + w;
      const unsigned int* srow = (const unsigned int*)(flat + (size_t)sidx[k]*FEATS);
      ((unsigned int*)spir)[k*64 + lane] = srow[lane];
    }
    __syncthreads();

    // ---- GEMM1: tmp[c][s] = sum_k spir[k][c] * perm[k][s]  (M=128,N=20->32,K=20->32) ----
    short8 afr[2], bfr[2];
    #pragma unroll
    for(int mt=0; mt<2; mt++){
      int c0 = w*32 + mt*16 + l15;
      short8 v;
      #pragma unroll
      for(int j=0;j<8;j++) v[j] = (short)spir[(lg*8+j)*128 + c0];
      afr[mt] = v;
    }
    #pragma unroll
    for(int nt=0; nt<2; nt++){
      int s0 = nt*16 + l15;
      short8 v;
      #pragma unroll
      for(int j=0;j<8;j++) v[j] = (short)perm_s[(lg*8+j)*32 + s0];
      bfr[nt] = v;
    }
    f32x4 acc1[2][2];
    #pragma unroll
    for(int mt=0; mt<2; mt++)
      #pragma unroll
      for(int nt=0; nt<2; nt++){
        f32x4 z = {0.f,0.f,0.f,0.f};
        acc1[mt][nt] = __builtin_amdgcn_mfma_f32_16x16x32_bf16(afr[mt], bfr[nt], z, 0,0,0);
      }

    // store tmp in .view([20,128]) layout with XOR swizzle (byte ^= (row&7)<<4)
    #pragma unroll
    for(int mt=0; mt<2; mt++)
      #pragma unroll
      for(int nt=0; nt<2; nt++){
        int s = nt*16 + l15;
        if(s < KK){
          #pragma unroll
          for(int r=0;r<4;r++){
            int c = w*32 + mt*16 + lg*4 + r;
            int fidx = c*20 + s;
            int row = fidx >> 7, col = fidx & 127;
            int byt = (row*256 + col*2) ^ ((row&7)<<4);
            *(unsigned short*)((char*)tmp + byt) = f2bf(acc1[mt][nt][r]);
          }
        }
      }
    __syncthreads();

    // ---- GEMM2: Y[o][kp] = sum_c' W[o][c'] * tmp[kp][c']  (M=64,N=20->32,K=128) ----
    f32x4 acc2[2] = {{0.f,0.f,0.f,0.f},{0.f,0.f,0.f,0.f}};
    #pragma unroll
    for(int ks=0; ks<4; ks++){
      #pragma unroll
      for(int nt=0; nt<2; nt++){
        int kp = nt*16 + l15;
        int byt = (kp*256 + ks*64 + lg*16) ^ ((kp&7)<<4);
        short8 bf = *(const short8*)((const char*)tmp + byt);
        acc2[nt] = __builtin_amdgcn_mfma_f32_16x16x32_bf16(wf[ks], bf, acc2[nt], 0,0,0);
      }
    }

    // ---- epilogue: max over kp (mask pad), +bias, store, BN partials ----
    #pragma unroll
    for(int r=0;r<4;r++){
      float m  = acc2[0][r];
      float v1 = (l15 < 4) ? acc2[1][r] : -3.4e38f;
      m = fmaxf(m, v1);
      #pragma unroll
      for(int off=1; off<16; off<<=1) m = fmaxf(m, __shfl_xor(m, off));
      if(l15 == 0){
        int o = w*16 + lg*4 + r;
        float y = m + bias[r];
        int bb = p >> 12, nn = p & (NPTS-1);
        out[((size_t)bb*OUTC + o)*NPTS + nn] = y;
        bsum[r] += y; bsq[r] += y*y;
      }
    }
  }

  if(l15 == 0){
    int o = w*16 + lg*4;
    #pragma unroll
    for(int r=0;r<4;r++){
      atomicAdd(&stats[o+r],    bsum[r]);
      atomicAdd(&stats[64+o+r], bsq[r]);
    }
  }
}

__global__ void k_finalize(const float* __restrict__ stats,
                           const float* __restrict__ gamma,
                           const float* __restrict__ beta,
                           float* __restrict__ ss){
  int o = threadIdx.x;   // 64
  float inv = 1.f/(float)PTOT;
  float mean = stats[o]*inv;
  float var  = stats[64+o]*inv - mean*mean;
  float rstd = rsqrtf(var + 1e-5f);
  float sc = gamma[o]*rstd;
  ss[o] = sc;
  ss[64+o] = beta[o] - mean*sc;
}

__global__ void k_bn(float* __restrict__ out, const float* __restrict__ ss){
  int i = blockIdx.x*256 + threadIdx.x;     // over float4s
  float4 v = ((float4*)out)[i];
  int o = (i >> 10) & 63;                   // 4*i >> 12
  float sc = ss[o], sh = ss[64+o];
  v.x = v.x*sc + sh; v.y = v.y*sc + sh; v.z = v.z*sc + sh; v.w = v.w*sc + sh;
  ((float4*)out)[i] = v;
}

extern "C" void kernel_launch(void* const* d_in, const int* in_sizes, int n_in,
                              void* d_out, int out_size, void* d_ws, size_t ws_size,
                              hipStream_t stream){
  (void)in_sizes; (void)n_in; (void)ws_size;
  const float* feature    = (const float*)d_in[0];
  const float* permatrix  = (const float*)d_in[1];
  const float* conv_w     = (const float*)d_in[2];
  const float* conv_b     = (const float*)d_in[3];
  const float* bn_gamma   = (const float*)d_in[4];
  const float* bn_beta    = (const float*)d_in[5];
  const int*   sp_idx     = (const int*)d_in[6];
  float* out = (float*)d_out;

  unsigned short* flat = (unsigned short*)d_ws;                       // 8 MB
  float* stats = (float*)((char*)d_ws + (size_t)8*1024*1024);         // 128 f32
  float* ss    = stats + 128;                                         // 128 f32

  hipMemsetAsync(stats, 0, 128*sizeof(float), stream);

  dim3 gT(NPTS/32, FEATS/32, BATCH), bT(32,8);
  k_transpose<<<gT, bT, 0, stream>>>(feature, flat);

  k_main<<<dim3(PTOT/8), dim3(256), 0, stream>>>(flat, permatrix, conv_w, conv_b,
                                                 sp_idx, out, stats);

  k_finalize<<<dim3(1), dim3(64), 0, stream>>>(stats, bn_gamma, bn_beta, ss);

  k_bn<<<dim3(out_size/4/256), dim3(256), 0, stream>>>(out, ss);
}